// Round 11
// baseline (355.237 us; speedup 1.0000x reference)
//
#include <hip/hip_runtime.h>

// BinarizeLinear: out[65536,1024] = x @ sign(W)^T + bias
// Round 11: ABLATION. Three dispatches:
//   1. wprep            (R6 exact)               ~8 us
//   2. ablate_nostage   (R6 geometry, NO in-loop staging: ds_read+MFMA+barrier
//                        only; garbage output)    = the unknown being measured
//   3. binlin128x256    (R6 exact, CORRECT, last  ~225 us; overwrites d_out)
// Read: V_nostage = bench_total - 233 us. Pre-committed decision rule in
// the round notes (<=115 -> bandwidth route; >=150 -> structure route).

typedef __bf16 bf16x8 __attribute__((ext_vector_type(8)));
typedef float  f32x4  __attribute__((ext_vector_type(4)));

constexpr int Mdim = 65536, Ndim = 1024, Kdim = 1024;
constexpr int NKT = Kdim / 32;                     // 32 K-steps (BK=32)

typedef const __attribute__((address_space(1))) char ga_char;
typedef __attribute__((address_space(3))) char lds_char;
__device__ __forceinline__ void gload16(const void* g, void* l) {
    __builtin_amdgcn_global_load_lds((ga_char*)g, (lds_char*)l, 16, 0, 0);
}
__device__ __forceinline__ f32x4 mfma16(bf16x8 a, bf16x8 b, f32x4 c) {
    return __builtin_amdgcn_mfma_f32_16x16x32_bf16(a, b, c, 0, 0, 0);
}

// ---- prepass: sign(W) -> bf16, frag-linear image (R6 exact) ----
__global__ __launch_bounds__(256)
void wprep_kernel(const float* __restrict__ W, __bf16* __restrict__ WS) {
    const int id   = blockIdx.x * 256 + threadIdx.x;   // 131072
    const int colb = id >> 15;
    const int kt   = (id >> 10) & 31;
    const int g    = id & 1023;
    const int nb   = g >> 6;
    const int lane = g & 63;
    const int row  = colb * 256 + nb * 16 + (lane & 15);
    const int col  = kt * 32 + (lane >> 4) * 8;
    const float* src = W + (size_t)row * Kdim + col;
    f32x4 a = *(const f32x4*)src;
    f32x4 b = *(const f32x4*)(src + 4);
    bf16x8 o;
#pragma unroll
    for (int e = 0; e < 4; ++e) {
        o[e]     = (__bf16)(float)((a[e] > 0.f) - (a[e] < 0.f));
        o[e + 4] = (__bf16)(float)((b[e] > 0.f) - (b[e] < 0.f));
    }
    *(bf16x8*)(WS + (size_t)id * 8) = o;
}

// ---- V_nostage: R6 loop minus ALL in-loop staging ----
__global__ __launch_bounds__(512, 4)
void ablate_nostage(const float* __restrict__ X, const __bf16* __restrict__ WS,
                    const float* __restrict__ bias, float* __restrict__ out)
{
    __shared__ __align__(16) char Alc[2][128 * 80];
    __shared__ __align__(16) __bf16 Bl[2][256 * 32];
    constexpr int mNWG = (Mdim / 128) * (Ndim / 256);   // 2048
    const int swz  = (blockIdx.x & 7) * (mNWG / 8) + (blockIdx.x >> 3);
    const int colb = swz & 3;
    const int rowb = swz >> 2;
    const int row0 = rowb * 128;
    const int tid  = threadIdx.x;
    const int lane = tid & 63;
    const int wid  = tid >> 6;
    const int wr   = wid >> 2;
    const int wcn  = wid & 3;
    const int fr   = lane & 15;
    const int hq   = lane >> 4;
    const int a_r  = tid >> 2;
    const int a_c  = (tid & 3) * 8;
    const float* Xb = X + (size_t)(row0 + a_r) * Kdim + a_c;
    const __bf16* WSb = WS + (size_t)colb * 262144;

    f32x4 ra[2];
    auto GLA = [&](int kt) {
        const float* p = Xb + kt * 32;
        ra[0] = *(const f32x4*)p;
        ra[1] = *(const f32x4*)(p + 4);
    };
    auto DSWA = [&](int buf) {
        bf16x8 v;
#pragma unroll
        for (int e = 0; e < 4; ++e) {
            v[e] = (__bf16)ra[0][e]; v[e + 4] = (__bf16)ra[1][e];
        }
        *(bf16x8*)(&Alc[buf][a_r * 80 + a_c * 2]) = v;
    };
    auto GLB = [&](int buf, int kt) {
        const __bf16* s = WSb + (size_t)kt * 8192 + wid * 1024 + lane * 8;
        gload16(s,       &Bl[buf][wid * 1024]);
        gload16(s + 512, &Bl[buf][wid * 1024 + 512]);
    };
    auto lda = [&](int buf, int i) -> bf16x8 {
        const int row = wr * 64 + i * 16 + fr;
        return *(const bf16x8*)(&Alc[buf][row * 80 + hq * 16]);
    };
    auto ldb = [&](int buf, int j) -> bf16x8 {
        return *(const bf16x8*)(&Bl[buf][(wcn * 4 + j) * 512 + lane * 8]);
    };

    f32x4 acc[4][4] = {};

    // prologue: stage BOTH buffers once (tiles 0 and 1), then never again
    GLA(0); GLB(0, 0); DSWA(0);
    GLA(1); GLB(1, 1); DSWA(1);
    __syncthreads();

    for (int t = 0; t < NKT; ++t) {
        const int cur = t & 1;
        bf16x8 af[4];
#pragma unroll
        for (int i = 0; i < 4; ++i) af[i] = lda(cur, i);
        __builtin_amdgcn_s_setprio(1);
#pragma unroll
        for (int j = 0; j < 4; ++j) {
            bf16x8 bfr = ldb(cur, j);
#pragma unroll
            for (int i = 0; i < 4; ++i)
                acc[i][j] = mfma16(af[i], bfr, acc[i][j]);
        }
        __builtin_amdgcn_s_setprio(0);
        // same barrier cadence as R6 (1/tile), no drain (nothing staged);
        // "memory" clobber forces the LDS re-reads each iteration.
        asm volatile("s_barrier" ::: "memory");
    }

    const int orow = row0 + wr * 64 + hq * 4;
    const int ocol = colb * 256 + wcn * 64 + fr;
#pragma unroll
    for (int j = 0; j < 4; ++j) {
        const float bv = bias[ocol + j * 16];
#pragma unroll
        for (int i = 0; i < 4; ++i)
#pragma unroll
            for (int r = 0; r < 4; ++r)
                out[(size_t)(orow + i * 16 + r) * Ndim + (ocol + j * 16)] =
                    acc[i][j][r] + bv;   // garbage values; overwritten by V0
    }
}

// ---- V0: R6 exact (correct, runs LAST) ----
__global__ __launch_bounds__(512, 4)
void binlin128x256(const float* __restrict__ X, const __bf16* __restrict__ WS,
                   const float* __restrict__ bias, float* __restrict__ out)
{
    __shared__ __align__(16) char Alc[2][128 * 80];
    __shared__ __align__(16) __bf16 Bl[2][256 * 32];
    constexpr int mNWG = (Mdim / 128) * (Ndim / 256);   // 2048
    const int swz  = (blockIdx.x & 7) * (mNWG / 8) + (blockIdx.x >> 3);
    const int colb = swz & 3;
    const int rowb = swz >> 2;
    const int row0 = rowb * 128;
    const int tid  = threadIdx.x;
    const int lane = tid & 63;
    const int wid  = tid >> 6;
    const int wr   = wid >> 2;
    const int wcn  = wid & 3;
    const int fr   = lane & 15;
    const int hq   = lane >> 4;
    const int a_r  = tid >> 2;
    const int a_c  = (tid & 3) * 8;
    const float* Xb = X + (size_t)(row0 + a_r) * Kdim + a_c;
    const __bf16* WSb = WS + (size_t)colb * 262144;

    f32x4 ra[2];
    auto GLA = [&](int kt) {
        const float* p = Xb + kt * 32;
        ra[0] = *(const f32x4*)p;
        ra[1] = *(const f32x4*)(p + 4);
    };
    auto DSWA = [&](int buf) {
        bf16x8 v;
#pragma unroll
        for (int e = 0; e < 4; ++e) {
            v[e] = (__bf16)ra[0][e]; v[e + 4] = (__bf16)ra[1][e];
        }
        *(bf16x8*)(&Alc[buf][a_r * 80 + a_c * 2]) = v;
    };
    auto GLB = [&](int buf, int kt) {
        const __bf16* s = WSb + (size_t)kt * 8192 + wid * 1024 + lane * 8;
        gload16(s,       &Bl[buf][wid * 1024]);
        gload16(s + 512, &Bl[buf][wid * 1024 + 512]);
    };
    auto lda = [&](int buf, int i) -> bf16x8 {
        const int row = wr * 64 + i * 16 + fr;
        return *(const bf16x8*)(&Alc[buf][row * 80 + hq * 16]);
    };
    auto ldb = [&](int buf, int j) -> bf16x8 {
        return *(const bf16x8*)(&Bl[buf][(wcn * 4 + j) * 512 + lane * 8]);
    };

    f32x4 acc[4][4] = {};
    GLA(0); GLB(0, 0); DSWA(0);
    __syncthreads();

    int cur = 0;
    for (int t = 0; t < NKT; ++t) {
        const int nxt = cur ^ 1;
        const bool pre = (t + 1 < NKT);
        if (pre) { GLA(t + 1); GLB(nxt, t + 1); }
        bf16x8 af[4];
#pragma unroll
        for (int i = 0; i < 4; ++i) af[i] = lda(cur, i);
        __builtin_amdgcn_s_setprio(1);
#pragma unroll
        for (int j = 0; j < 4; ++j) {
            bf16x8 bfr = ldb(cur, j);
#pragma unroll
            for (int i = 0; i < 4; ++i)
                acc[i][j] = mfma16(af[i], bfr, acc[i][j]);
        }
        __builtin_amdgcn_s_setprio(0);
        if (pre) { DSWA(nxt); __syncthreads(); }
        cur = nxt;
    }

    const int orow = row0 + wr * 64 + hq * 4;
    const int ocol = colb * 256 + wcn * 64 + fr;
#pragma unroll
    for (int j = 0; j < 4; ++j) {
        const float bv = bias[ocol + j * 16];
#pragma unroll
        for (int i = 0; i < 4; ++i)
#pragma unroll
            for (int r = 0; r < 4; ++r)
                out[(size_t)(orow + i * 16 + r) * Ndim + (ocol + j * 16)] =
                    acc[i][j][r] + bv;
    }
}

// ---- fallback (ws < 2MB): reg-staged 128x128, inline sign ----
__global__ __launch_bounds__(256)
void binlin_fallback(const float* __restrict__ X, const float* __restrict__ Wf,
                     const float* __restrict__ bias, float* __restrict__ out)
{
    __shared__ __align__(16) __bf16 Al[2][128][32];
    __shared__ __align__(16) __bf16 Bl[2][128][32];
    constexpr int NT = Kdim / 32;
    const int swz  = (blockIdx.x & 7) * (4096 / 8) + (blockIdx.x >> 3);
    const int colb = swz & 7, rowb = swz >> 3;
    const int row0 = rowb * 128, col0 = colb * 128;
    const int tid = threadIdx.x, lane = tid & 63, wid = tid >> 6;
    const int wr = wid >> 1, wc = wid & 1;
    const int sr = tid >> 2, sc = (tid & 3) * 8;
    const float* Xb = X + (size_t)row0 * Kdim;
    const float* Wb = Wf + (size_t)col0 * Kdim;
    f32x4 ra[2][2], rb[2][2];
    auto GL = [&](int k0) {
#pragma unroll
        for (int p = 0; p < 2; ++p) {
            const float* sa = Xb + (size_t)(p * 64 + sr) * Kdim + k0 + sc;
            ra[p][0] = *(const f32x4*)sa; ra[p][1] = *(const f32x4*)(sa + 4);
            const float* sb = Wb + (size_t)(p * 64 + sr) * Kdim + k0 + sc;
            rb[p][0] = *(const f32x4*)sb; rb[p][1] = *(const f32x4*)(sb + 4);
        }
    };
    auto DSW = [&](int buf) {
#pragma unroll
        for (int p = 0; p < 2; ++p) {
            bf16x8 va, vb;
#pragma unroll
            for (int e = 0; e < 4; ++e) {
                va[e] = (__bf16)ra[p][0][e]; va[e + 4] = (__bf16)ra[p][1][e];
                float a = rb[p][0][e], b = rb[p][1][e];
                vb[e] = (__bf16)(float)((a > 0.f) - (a < 0.f));
                vb[e + 4] = (__bf16)(float)((b > 0.f) - (b < 0.f));
            }
            *(bf16x8*)&Al[buf][p * 64 + sr][sc] = va;
            *(bf16x8*)&Bl[buf][p * 64 + sr][sc] = vb;
        }
    };
    f32x4 acc[4][4] = {};
    const int fr = lane & 15, ks = (lane >> 4) * 8;
    auto COMP = [&](int buf) {
        bf16x8 af[4], bf[4];
#pragma unroll
        for (int i = 0; i < 4; ++i) af[i] = *(const bf16x8*)&Al[buf][wr * 64 + fr + i * 16][ks];
#pragma unroll
        for (int j = 0; j < 4; ++j) bf[j] = *(const bf16x8*)&Bl[buf][wc * 64 + fr + j * 16][ks];
#pragma unroll
        for (int i = 0; i < 4; ++i)
#pragma unroll
            for (int j = 0; j < 4; ++j)
                acc[i][j] = mfma16(af[i], bf[j], acc[i][j]);
    };
    GL(0); DSW(0); __syncthreads();
    int cur = 0;
    for (int t = 0; t < NT; ++t) {
        if (t + 1 < NT) GL((t + 1) * 32);
        COMP(cur);
        if (t + 1 < NT) { DSW(cur ^ 1); __syncthreads(); cur ^= 1; }
    }
    const int orow = row0 + wr * 64 + (lane >> 4) * 4;
    const int ocol = col0 + wc * 64 + fr;
#pragma unroll
    for (int j = 0; j < 4; ++j) {
        const float bv = bias[ocol + j * 16];
#pragma unroll
        for (int i = 0; i < 4; ++i)
#pragma unroll
            for (int r = 0; r < 4; ++r)
                out[(size_t)(orow + i * 16 + r) * Ndim + (ocol + j * 16)] = acc[i][j][r] + bv;
    }
}

extern "C" void kernel_launch(void* const* d_in, const int* in_sizes, int n_in,
                              void* d_out, int out_size, void* d_ws, size_t ws_size,
                              hipStream_t stream) {
    const float* x  = (const float*)d_in[0];
    const float* w  = (const float*)d_in[1];
    const float* b  = (const float*)d_in[2];
    float* out      = (float*)d_out;

    constexpr size_t WS_BYTES = (size_t)Ndim * Kdim * sizeof(__bf16);  // 2 MB

    if (ws_size >= WS_BYTES) {
        __bf16* ws = (__bf16*)d_ws;
        wprep_kernel<<<dim3(512), dim3(256), 0, stream>>>(w, ws);
        // ablation probe (garbage output, timed):
        ablate_nostage<<<dim3(2048), dim3(512), 0, stream>>>(x, ws, b, out);
        // correct kernel LAST (fully overwrites d_out):
        binlin128x256<<<dim3(2048), dim3(512), 0, stream>>>(x, ws, b, out);
    } else {
        binlin_fallback<<<dim3(4096), dim3(256), 0, stream>>>(x, w, b, out);
    }
}

// Round 12
// 220.499 us; speedup vs baseline: 1.6111x; 1.6111x over previous
//
#include <hip/hip_runtime.h>

// BinarizeLinear: out[65536,1024] = x @ sign(W)^T + bias
// Round 12: int8 route (ablation R11 showed the bf16 family is LDS-BW-bound:
// 88KB LDS traffic per block-K-step, ~70-100% pipe saturation; schedules
// can't fix that). i8 mfma 16x16x64 halves LDS bytes/FLOP, halves MFMA
// floor, halves K-steps. W = sign() is EXACT in i8. x quantized per-row
// (q = rint(x*127/rowmax), dequant in epilogue: out = acc*rowmax/127 + b).
// Prepass 1: per-row absmax + quantize + write frag-linear i8 image (64MB).
// Prepass 2: sign(W) -> i8 frag-linear image (1MB).
// GEMM: BM=128 BN=256 BK=64 (16 steps), 8 waves (2Mx4N), per-wave 64x64,
// both operands pure global_load_lds (no cvt, no reg staging), frag-linear
// LDS (conflict-free), R6 2-phase loop, XCD swizzle.
// ws layout: [W image 1MB][scales 256KB][x image 64MB] = 65.25MB (R8 proved
// ws >= 130MB available). Fallbacks: R6 bf16 (ws>=2MB), reg-staged (else).

typedef __bf16 bf16x8 __attribute__((ext_vector_type(8)));
typedef float  f32x4  __attribute__((ext_vector_type(4)));
typedef int    i32x4  __attribute__((ext_vector_type(4)));
typedef char   i8x16  __attribute__((ext_vector_type(16)));

constexpr int Mdim = 65536, Ndim = 1024, Kdim = 1024;

typedef const __attribute__((address_space(1))) char ga_char;
typedef __attribute__((address_space(3))) char lds_char;
__device__ __forceinline__ void gload16(const void* g, void* l) {
    __builtin_amdgcn_global_load_lds((ga_char*)g, (lds_char*)l, 16, 0, 0);
}
__device__ __forceinline__ f32x4 mfma16(bf16x8 a, bf16x8 b, f32x4 c) {
    return __builtin_amdgcn_mfma_f32_16x16x32_bf16(a, b, c, 0, 0, 0);
}

// =====================  i8 path  =====================

// ---- prepass 1: x -> per-row-scaled i8, frag-linear image ----
// One wave per row. Lane l owns cols [16l, 16l+16).
// Image addr for (row r, chunk c): rowb=r>>7, mb=(r>>4)&7, fr=r&15,
//   kt=c>>2, hq=c&3 -> (rowb*16+kt)*8192 + mb*1024 + (hq*16+fr)*16
__global__ __launch_bounds__(256)
void xquant_kernel(const float* __restrict__ X, char* __restrict__ XI,
                   float* __restrict__ SC) {
    const int lane = threadIdx.x & 63;
    const int row  = blockIdx.x * 4 + (threadIdx.x >> 6);
    const float* src = X + (size_t)row * Kdim + lane * 16;
    f32x4 v[4];
#pragma unroll
    for (int k = 0; k < 4; ++k) v[k] = *(const f32x4*)(src + k * 4);
    float m = 0.f;
#pragma unroll
    for (int k = 0; k < 4; ++k)
#pragma unroll
        for (int e = 0; e < 4; ++e) m = fmaxf(m, fabsf(v[k][e]));
#pragma unroll
    for (int i = 1; i < 64; i <<= 1) m = fmaxf(m, __shfl_xor(m, i));
    const float s = (m > 0.f) ? 127.f / m : 0.f;
    i8x16 o;
#pragma unroll
    for (int k = 0; k < 4; ++k)
#pragma unroll
        for (int e = 0; e < 4; ++e)
            o[k * 4 + e] = (char)__float2int_rn(v[k][e] * s);
    const int rowb = row >> 7, mb = (row >> 4) & 7, fr = row & 15;
    const int kt = lane >> 2, hq = lane & 3;
    *(i8x16*)(XI + (size_t)(rowb * 16 + kt) * 8192 + mb * 1024
              + (hq * 16 + fr) * 16) = o;
    if (lane == 0) SC[row] = m * (1.f / 127.f);
}

// ---- prepass 2: sign(W) -> i8 frag-linear image (1MB) ----
// id -> (colb, kt, nb, lane); lane l: col n = colb*256+nb*16+(l&15),
// k = kt*64 + (l>>4)*16 .. +16
__global__ __launch_bounds__(256)
void wsign8_kernel(const float* __restrict__ W, char* __restrict__ WI) {
    const int id   = blockIdx.x * 256 + threadIdx.x;   // 65536 threads
    const int lane = id & 63;
    const int nb   = (id >> 6) & 15;
    const int kt   = (id >> 10) & 15;
    const int colb = id >> 14;                          // 0..3
    const float* src = W + (size_t)(colb * 256 + nb * 16 + (lane & 15)) * Kdim
                         + kt * 64 + (lane >> 4) * 16;
    i8x16 o;
#pragma unroll
    for (int k = 0; k < 4; ++k) {
        f32x4 v = *(const f32x4*)(src + k * 4);
#pragma unroll
        for (int e = 0; e < 4; ++e)
            o[k * 4 + e] = (char)((v[e] > 0.f) - (v[e] < 0.f));
    }
    *(i8x16*)(WI + (size_t)id * 16) = o;
}

// ---- main GEMM: i8, pure-DMA staging, R6 2-phase loop ----
__global__ __launch_bounds__(512, 4)
void binlin_i8(const char* __restrict__ XI, const char* __restrict__ WI,
               const float* __restrict__ SC, const float* __restrict__ bias,
               float* __restrict__ out)
{
    __shared__ __align__(16) char Al[2][8192];    // 128x64 i8, frag-linear
    __shared__ __align__(16) char Bl[2][16384];   // 256x64 i8, frag-linear

    constexpr int NWG = (Mdim / 128) * (Ndim / 256);   // 2048
    const int swz  = (blockIdx.x & 7) * (NWG / 8) + (blockIdx.x >> 3);
    const int colb = swz & 3;
    const int rowb = swz >> 2;
    const int row0 = rowb * 128;

    const int tid  = threadIdx.x;
    const int lane = tid & 63;
    const int wid  = tid >> 6;
    const int wr   = wid >> 2;        // M half (64 rows)
    const int wcn  = wid & 3;         // N quarter (64 cols)
    const int fr   = lane & 15;
    const int hq   = lane >> 4;

    const char* XIb = XI + (size_t)rowb * 16 * 8192;
    const char* WIb = WI + (size_t)colb * 16 * 16384;

    // stage tile kt into buf: A 8KB (1 gload16/thread), B 16KB (2/thread)
    auto STAGE = [&](int buf, int kt) {
        gload16(XIb + (size_t)kt * 8192 + tid * 16, &Al[buf][tid * 16]);
        const char* bsrc = WIb + (size_t)kt * 16384 + tid * 16;
        gload16(bsrc,        &Bl[buf][tid * 16]);
        gload16(bsrc + 8192, &Bl[buf][8192 + tid * 16]);
    };
    auto lda = [&](int buf, int i) -> i32x4 {
        return *(const i32x4*)(&Al[buf][(wr * 4 + i) * 1024 + lane * 16]);
    };
    auto ldb = [&](int buf, int j) -> i32x4 {
        return *(const i32x4*)(&Bl[buf][(wcn * 4 + j) * 1024 + lane * 16]);
    };

    i32x4 acc[4][4] = {};

    STAGE(0, 0);
    __syncthreads();

    constexpr int NKT = Kdim / 64;    // 16
    int cur = 0;
    for (int t = 0; t < NKT; ++t) {
        const int nxt = cur ^ 1;
        const bool pre = (t + 1 < NKT);
        if (pre) STAGE(nxt, t + 1);   // in flight during COMP

        i32x4 af[4];
#pragma unroll
        for (int i = 0; i < 4; ++i) af[i] = lda(cur, i);
        __builtin_amdgcn_s_setprio(1);
#pragma unroll
        for (int j = 0; j < 4; ++j) {
            i32x4 bf = ldb(cur, j);
#pragma unroll
            for (int i = 0; i < 4; ++i)
                acc[i][j] = __builtin_amdgcn_mfma_i32_16x16x64_i8(
                    af[i], bf, acc[i][j], 0, 0, 0);
        }
        __builtin_amdgcn_s_setprio(0);

        if (pre) __syncthreads();     // drains gload_lds, publishes nxt
        cur = nxt;
    }

    // epilogue: row = orow + i*16 + r, col = ocol + j*16; dequant per row
    const int orow = row0 + wr * 64 + hq * 4;
    const int ocol = colb * 256 + wcn * 64 + fr;
    f32x4 sv[4];
#pragma unroll
    for (int i = 0; i < 4; ++i) sv[i] = *(const f32x4*)(SC + orow + i * 16);
#pragma unroll
    for (int j = 0; j < 4; ++j) {
        const float bv = bias[ocol + j * 16];
#pragma unroll
        for (int i = 0; i < 4; ++i)
#pragma unroll
            for (int r = 0; r < 4; ++r)
                out[(size_t)(orow + i * 16 + r) * Ndim + (ocol + j * 16)] =
                    (float)acc[i][j][r] * sv[i][r] + bv;
    }
}

// =====================  bf16 fallback paths  =====================

__global__ __launch_bounds__(256)
void wprep_kernel(const float* __restrict__ W, __bf16* __restrict__ WS) {
    const int id   = blockIdx.x * 256 + threadIdx.x;   // 131072
    const int colb = id >> 15;
    const int kt   = (id >> 10) & 31;
    const int g    = id & 1023;
    const int nb   = g >> 6;
    const int lane = g & 63;
    const int row  = colb * 256 + nb * 16 + (lane & 15);
    const int col  = kt * 32 + (lane >> 4) * 8;
    const float* src = W + (size_t)row * Kdim + col;
    f32x4 a = *(const f32x4*)src;
    f32x4 b = *(const f32x4*)(src + 4);
    bf16x8 o;
#pragma unroll
    for (int e = 0; e < 4; ++e) {
        o[e]     = (__bf16)(float)((a[e] > 0.f) - (a[e] < 0.f));
        o[e + 4] = (__bf16)(float)((b[e] > 0.f) - (b[e] < 0.f));
    }
    *(bf16x8*)(WS + (size_t)id * 8) = o;
}

__global__ __launch_bounds__(512, 4)
void binlin128x256(const float* __restrict__ X, const __bf16* __restrict__ WS,
                   const float* __restrict__ bias, float* __restrict__ out)
{
    __shared__ __align__(16) char Alc[2][128 * 80];
    __shared__ __align__(16) __bf16 Bl[2][256 * 32];
    constexpr int mNWG = (Mdim / 128) * (Ndim / 256);
    const int swz  = (blockIdx.x & 7) * (mNWG / 8) + (blockIdx.x >> 3);
    const int colb = swz & 3;
    const int rowb = swz >> 2;
    const int row0 = rowb * 128;
    const int tid  = threadIdx.x;
    const int lane = tid & 63;
    const int wid  = tid >> 6;
    const int wr   = wid >> 2;
    const int wcn  = wid & 3;
    const int fr   = lane & 15;
    const int hq   = lane >> 4;
    const int a_r  = tid >> 2;
    const int a_c  = (tid & 3) * 8;
    const float* Xb = X + (size_t)(row0 + a_r) * Kdim + a_c;
    const __bf16* WSb = WS + (size_t)colb * 262144;
    f32x4 ra[2];
    auto GLA = [&](int kt) {
        const float* p = Xb + kt * 32;
        ra[0] = *(const f32x4*)p;
        ra[1] = *(const f32x4*)(p + 4);
    };
    auto DSWA = [&](int buf) {
        bf16x8 v;
#pragma unroll
        for (int e = 0; e < 4; ++e) {
            v[e] = (__bf16)ra[0][e]; v[e + 4] = (__bf16)ra[1][e];
        }
        *(bf16x8*)(&Alc[buf][a_r * 80 + a_c * 2]) = v;
    };
    auto GLB = [&](int buf, int kt) {
        const __bf16* s = WSb + (size_t)kt * 8192 + wid * 1024 + lane * 8;
        gload16(s,       &Bl[buf][wid * 1024]);
        gload16(s + 512, &Bl[buf][wid * 1024 + 512]);
    };
    auto lda = [&](int buf, int i) -> bf16x8 {
        const int row = wr * 64 + i * 16 + fr;
        return *(const bf16x8*)(&Alc[buf][row * 80 + hq * 16]);
    };
    auto ldb = [&](int buf, int j) -> bf16x8 {
        return *(const bf16x8*)(&Bl[buf][(wcn * 4 + j) * 512 + lane * 8]);
    };
    f32x4 acc[4][4] = {};
    GLA(0); GLB(0, 0); DSWA(0);
    __syncthreads();
    int cur = 0;
    for (int t = 0; t < 32; ++t) {
        const int nxt = cur ^ 1;
        const bool pre = (t + 1 < 32);
        if (pre) { GLA(t + 1); GLB(nxt, t + 1); }
        bf16x8 af[4];
#pragma unroll
        for (int i = 0; i < 4; ++i) af[i] = lda(cur, i);
        __builtin_amdgcn_s_setprio(1);
#pragma unroll
        for (int j = 0; j < 4; ++j) {
            bf16x8 bfr = ldb(cur, j);
#pragma unroll
            for (int i = 0; i < 4; ++i)
                acc[i][j] = mfma16(af[i], bfr, acc[i][j]);
        }
        __builtin_amdgcn_s_setprio(0);
        if (pre) { DSWA(nxt); __syncthreads(); }
        cur = nxt;
    }
    const int orow = row0 + wr * 64 + hq * 4;
    const int ocol = colb * 256 + wcn * 64 + fr;
#pragma unroll
    for (int j = 0; j < 4; ++j) {
        const float bv = bias[ocol + j * 16];
#pragma unroll
        for (int i = 0; i < 4; ++i)
#pragma unroll
            for (int r = 0; r < 4; ++r)
                out[(size_t)(orow + i * 16 + r) * Ndim + (ocol + j * 16)] =
                    acc[i][j][r] + bv;
    }
}

__global__ __launch_bounds__(256)
void binlin_fallback(const float* __restrict__ X, const float* __restrict__ Wf,
                     const float* __restrict__ bias, float* __restrict__ out)
{
    __shared__ __align__(16) __bf16 Al[2][128][32];
    __shared__ __align__(16) __bf16 Bl[2][128][32];
    const int swz  = (blockIdx.x & 7) * (4096 / 8) + (blockIdx.x >> 3);
    const int colb = swz & 7, rowb = swz >> 3;
    const int row0 = rowb * 128, col0 = colb * 128;
    const int tid = threadIdx.x, lane = tid & 63, wid = tid >> 6;
    const int wr = wid >> 1, wc = wid & 1;
    const int sr = tid >> 2, sc = (tid & 3) * 8;
    const float* Xb = X + (size_t)row0 * Kdim;
    const float* Wb = Wf + (size_t)col0 * Kdim;
    f32x4 ra[2][2], rb[2][2];
    auto GL = [&](int k0) {
#pragma unroll
        for (int p = 0; p < 2; ++p) {
            const float* sa = Xb + (size_t)(p * 64 + sr) * Kdim + k0 + sc;
            ra[p][0] = *(const f32x4*)sa; ra[p][1] = *(const f32x4*)(sa + 4);
            const float* sb = Wb + (size_t)(p * 64 + sr) * Kdim + k0 + sc;
            rb[p][0] = *(const f32x4*)sb; rb[p][1] = *(const f32x4*)(sb + 4);
        }
    };
    auto DSW = [&](int buf) {
#pragma unroll
        for (int p = 0; p < 2; ++p) {
            bf16x8 va, vb;
#pragma unroll
            for (int e = 0; e < 4; ++e) {
                va[e] = (__bf16)ra[p][0][e]; va[e + 4] = (__bf16)ra[p][1][e];
                float a = rb[p][0][e], b = rb[p][1][e];
                vb[e] = (__bf16)(float)((a > 0.f) - (a < 0.f));
                vb[e + 4] = (__bf16)(float)((b > 0.f) - (b < 0.f));
            }
            *(bf16x8*)&Al[buf][p * 64 + sr][sc] = va;
            *(bf16x8*)&Bl[buf][p * 64 + sr][sc] = vb;
        }
    };
    f32x4 acc[4][4] = {};
    const int fr = lane & 15, ks = (lane >> 4) * 8;
    auto COMP = [&](int buf) {
        bf16x8 af[4], bf[4];
#pragma unroll
        for (int i = 0; i < 4; ++i) af[i] = *(const bf16x8*)&Al[buf][wr * 64 + fr + i * 16][ks];
#pragma unroll
        for (int j = 0; j < 4; ++j) bf[j] = *(const bf16x8*)&Bl[buf][wc * 64 + fr + j * 16][ks];
#pragma unroll
        for (int i = 0; i < 4; ++i)
#pragma unroll
            for (int j = 0; j < 4; ++j)
                acc[i][j] = mfma16(af[i], bf[j], acc[i][j]);
    };
    GL(0); DSW(0); __syncthreads();
    int cur = 0;
    for (int t = 0; t < 32; ++t) {
        if (t + 1 < 32) GL((t + 1) * 32);
        COMP(cur);
        if (t + 1 < 32) { DSW(cur ^ 1); __syncthreads(); cur ^= 1; }
    }
    const int orow = row0 + wr * 64 + (lane >> 4) * 4;
    const int ocol = col0 + wc * 64 + fr;
#pragma unroll
    for (int j = 0; j < 4; ++j) {
        const float bv = bias[ocol + j * 16];
#pragma unroll
        for (int i = 0; i < 4; ++i)
#pragma unroll
            for (int r = 0; r < 4; ++r)
                out[(size_t)(orow + i * 16 + r) * Ndim + (ocol + j * 16)] = acc[i][j][r] + bv;
    }
}

extern "C" void kernel_launch(void* const* d_in, const int* in_sizes, int n_in,
                              void* d_out, int out_size, void* d_ws, size_t ws_size,
                              hipStream_t stream) {
    const float* x  = (const float*)d_in[0];
    const float* w  = (const float*)d_in[1];
    const float* b  = (const float*)d_in[2];
    float* out      = (float*)d_out;

    constexpr size_t WI_BYTES = (size_t)Ndim * Kdim;            // 1 MB (i8)
    constexpr size_t SC_BYTES = (size_t)Mdim * sizeof(float);   // 256 KB
    constexpr size_t XI_BYTES = (size_t)Mdim * Kdim;            // 64 MB (i8)
    constexpr size_t I8_TOTAL = WI_BYTES + SC_BYTES + XI_BYTES; // ~65.3 MB
    constexpr size_t WS_BYTES = (size_t)Ndim * Kdim * sizeof(__bf16); // 2 MB

    if (ws_size >= I8_TOTAL) {
        char*  wi = (char*)d_ws;
        float* sc = (float*)((char*)d_ws + WI_BYTES);
        char*  xi = (char*)d_ws + WI_BYTES + SC_BYTES;
        wsign8_kernel<<<dim3(256),   dim3(256), 0, stream>>>(w, wi);
        xquant_kernel<<<dim3(16384), dim3(256), 0, stream>>>(x, xi, sc);
        binlin_i8<<<dim3(2048), dim3(512), 0, stream>>>(xi, wi, sc, b, out);
    } else if (ws_size >= WS_BYTES) {
        __bf16* ws = (__bf16*)d_ws;
        wprep_kernel<<<dim3(512), dim3(256), 0, stream>>>(w, ws);
        binlin128x256<<<dim3(2048), dim3(512), 0, stream>>>(x, ws, b, out);
    } else {
        binlin_fallback<<<dim3(4096), dim3(256), 0, stream>>>(x, w, b, out);
    }
}

// Round 13
// 219.989 us; speedup vs baseline: 1.6148x; 1.0023x over previous
//
#include <hip/hip_runtime.h>

// BinarizeLinear: out[65536,1024] = x @ sign(W)^T + bias
// Round 13: R12 i8 route + ring-3 staging with counted vmcnt (the single
// structural change). GEMM: BM=128 BN=256 BK=64 (16 steps), 8 waves,
// per-wave 64x64, LDS ring of 3 slots (72 KB -> 2 blocks/CU), both operands
// pure global_load_lds from prepassed frag-linear i8 images. Per step:
// {STAGE tile t+2 (3 gload_lds) | ds_read frags slot t | setprio 16 MFMA |
//  vmcnt(3) (tile t+1 landed, t+2 in flight) | s_barrier}. Never vmcnt(0)
// mid-loop. Prepasses unchanged: per-row x quant (absmax 1.75 proven) +
// sign(W) i8 image.

typedef __bf16 bf16x8 __attribute__((ext_vector_type(8)));
typedef float  f32x4  __attribute__((ext_vector_type(4)));
typedef int    i32x4  __attribute__((ext_vector_type(4)));
typedef char   i8x16  __attribute__((ext_vector_type(16)));

constexpr int Mdim = 65536, Ndim = 1024, Kdim = 1024;

typedef const __attribute__((address_space(1))) char ga_char;
typedef __attribute__((address_space(3))) char lds_char;
__device__ __forceinline__ void gload16(const void* g, void* l) {
    __builtin_amdgcn_global_load_lds((ga_char*)g, (lds_char*)l, 16, 0, 0);
}
__device__ __forceinline__ f32x4 mfma16(bf16x8 a, bf16x8 b, f32x4 c) {
    return __builtin_amdgcn_mfma_f32_16x16x32_bf16(a, b, c, 0, 0, 0);
}

// =====================  i8 path  =====================

// ---- prepass 1: x -> per-row-scaled i8, frag-linear image (R12 exact) ----
__global__ __launch_bounds__(256)
void xquant_kernel(const float* __restrict__ X, char* __restrict__ XI,
                   float* __restrict__ SC) {
    const int lane = threadIdx.x & 63;
    const int row  = blockIdx.x * 4 + (threadIdx.x >> 6);
    const float* src = X + (size_t)row * Kdim + lane * 16;
    f32x4 v[4];
#pragma unroll
    for (int k = 0; k < 4; ++k) v[k] = *(const f32x4*)(src + k * 4);
    float m = 0.f;
#pragma unroll
    for (int k = 0; k < 4; ++k)
#pragma unroll
        for (int e = 0; e < 4; ++e) m = fmaxf(m, fabsf(v[k][e]));
#pragma unroll
    for (int i = 1; i < 64; i <<= 1) m = fmaxf(m, __shfl_xor(m, i));
    const float s = (m > 0.f) ? 127.f / m : 0.f;
    i8x16 o;
#pragma unroll
    for (int k = 0; k < 4; ++k)
#pragma unroll
        for (int e = 0; e < 4; ++e)
            o[k * 4 + e] = (char)__float2int_rn(v[k][e] * s);
    const int rowb = row >> 7, mb = (row >> 4) & 7, fr = row & 15;
    const int kt = lane >> 2, hq = lane & 3;
    *(i8x16*)(XI + (size_t)(rowb * 16 + kt) * 8192 + mb * 1024
              + (hq * 16 + fr) * 16) = o;
    if (lane == 0) SC[row] = m * (1.f / 127.f);
}

// ---- prepass 2: sign(W) -> i8 frag-linear image (R12 exact) ----
__global__ __launch_bounds__(256)
void wsign8_kernel(const float* __restrict__ W, char* __restrict__ WI) {
    const int id   = blockIdx.x * 256 + threadIdx.x;   // 65536 threads
    const int lane = id & 63;
    const int nb   = (id >> 6) & 15;
    const int kt   = (id >> 10) & 15;
    const int colb = id >> 14;                          // 0..3
    const float* src = W + (size_t)(colb * 256 + nb * 16 + (lane & 15)) * Kdim
                         + kt * 64 + (lane >> 4) * 16;
    i8x16 o;
#pragma unroll
    for (int k = 0; k < 4; ++k) {
        f32x4 v = *(const f32x4*)(src + k * 4);
#pragma unroll
        for (int e = 0; e < 4; ++e)
            o[k * 4 + e] = (char)((v[e] > 0.f) - (v[e] < 0.f));
    }
    *(i8x16*)(WI + (size_t)id * 16) = o;
}

// ---- main GEMM: i8, ring-3, counted vmcnt, one barrier/step ----
__global__ __launch_bounds__(512, 4)
void binlin_i8r3(const char* __restrict__ XI, const char* __restrict__ WI,
                 const float* __restrict__ SC, const float* __restrict__ bias,
                 float* __restrict__ out)
{
    __shared__ __align__(16) char Al[3][8192];    // ring: 3 x 8 KB
    __shared__ __align__(16) char Bl[3][16384];   // ring: 3 x 16 KB (72 KB tot)

    constexpr int NWG = (Mdim / 128) * (Ndim / 256);   // 2048
    const int swz  = (blockIdx.x & 7) * (NWG / 8) + (blockIdx.x >> 3);
    const int colb = swz & 3;
    const int rowb = swz >> 2;
    const int row0 = rowb * 128;

    const int tid  = threadIdx.x;
    const int lane = tid & 63;
    const int wid  = tid >> 6;
    const int wr   = wid >> 2;        // M half (64 rows)
    const int wcn  = wid & 3;         // N quarter (64 cols)
    const int fr   = lane & 15;
    const int hq   = lane >> 4;

    const char* XIb = XI + (size_t)rowb * 16 * 8192;
    const char* WIb = WI + (size_t)colb * 16 * 16384;

    // stage tile kt into ring slot: A 8KB (1 gload16/thread), B 16KB (2/thr)
    auto STAGE = [&](int buf, int kt) {
        gload16(XIb + (size_t)kt * 8192 + tid * 16, &Al[buf][tid * 16]);
        const char* bsrc = WIb + (size_t)kt * 16384 + tid * 16;
        gload16(bsrc,        &Bl[buf][tid * 16]);
        gload16(bsrc + 8192, &Bl[buf][8192 + tid * 16]);
    };
    auto lda = [&](int buf, int i) -> i32x4 {
        return *(const i32x4*)(&Al[buf][(wr * 4 + i) * 1024 + lane * 16]);
    };
    auto ldb = [&](int buf, int j) -> i32x4 {
        return *(const i32x4*)(&Bl[buf][(wcn * 4 + j) * 1024 + lane * 16]);
    };

    i32x4 acc[4][4] = {};

    // prologue: stage tiles 0,1 (6 loads); vmcnt(3) -> tile 0 landed,
    // tile 1's 3 loads stay in flight.
    STAGE(0, 0);
    STAGE(1, 1);
    asm volatile("s_waitcnt vmcnt(3)" ::: "memory");
    __builtin_amdgcn_sched_barrier(0);
    __builtin_amdgcn_s_barrier();

    constexpr int NKT = Kdim / 64;    // 16
    for (int t = 0; t < NKT; ++t) {
        const int cs = t % 3;                         // consume slot
        const int ss = (t + 2) % 3;                   // stage slot (!= cs)
        const int kt = (t + 2 < NKT) ? t + 2 : NKT - 1;  // uniform clamp
        STAGE(ss, kt);                                // 3 gload_lds, 2 steps ahead

        i32x4 af[4];
#pragma unroll
        for (int i = 0; i < 4; ++i) af[i] = lda(cs, i);
        __builtin_amdgcn_s_setprio(1);
#pragma unroll
        for (int j = 0; j < 4; ++j) {
            i32x4 bf = ldb(cs, j);
#pragma unroll
            for (int i = 0; i < 4; ++i)
                acc[i][j] = __builtin_amdgcn_mfma_i32_16x16x64_i8(
                    af[i], bf, acc[i][j], 0, 0, 0);
        }
        __builtin_amdgcn_s_setprio(0);

        // counted publish: all but newest 3 loads done => tile t+1 (issued a
        // full step ago) resident; tile t+2 stays in flight. Never 0.
        asm volatile("s_waitcnt vmcnt(3)" ::: "memory");
        __builtin_amdgcn_sched_barrier(0);
        __builtin_amdgcn_s_barrier();
    }

    // epilogue: row = orow + i*16 + r, col = ocol + j*16; per-row dequant
    const int orow = row0 + wr * 64 + hq * 4;
    const int ocol = colb * 256 + wcn * 64 + fr;
    f32x4 sv[4];
#pragma unroll
    for (int i = 0; i < 4; ++i) sv[i] = *(const f32x4*)(SC + orow + i * 16);
#pragma unroll
    for (int j = 0; j < 4; ++j) {
        const float bv = bias[ocol + j * 16];
#pragma unroll
        for (int i = 0; i < 4; ++i)
#pragma unroll
            for (int r = 0; r < 4; ++r)
                out[(size_t)(orow + i * 16 + r) * Ndim + (ocol + j * 16)] =
                    (float)acc[i][j][r] * sv[i][r] + bv;
    }
}

// =====================  bf16 fallback paths (R12 exact)  =====================

__global__ __launch_bounds__(256)
void wprep_kernel(const float* __restrict__ W, __bf16* __restrict__ WS) {
    const int id   = blockIdx.x * 256 + threadIdx.x;   // 131072
    const int colb = id >> 15;
    const int kt   = (id >> 10) & 31;
    const int g    = id & 1023;
    const int nb   = g >> 6;
    const int lane = g & 63;
    const int row  = colb * 256 + nb * 16 + (lane & 15);
    const int col  = kt * 32 + (lane >> 4) * 8;
    const float* src = W + (size_t)row * Kdim + col;
    f32x4 a = *(const f32x4*)src;
    f32x4 b = *(const f32x4*)(src + 4);
    bf16x8 o;
#pragma unroll
    for (int e = 0; e < 4; ++e) {
        o[e]     = (__bf16)(float)((a[e] > 0.f) - (a[e] < 0.f));
        o[e + 4] = (__bf16)(float)((b[e] > 0.f) - (b[e] < 0.f));
    }
    *(bf16x8*)(WS + (size_t)id * 8) = o;
}

__global__ __launch_bounds__(512, 4)
void binlin128x256(const float* __restrict__ X, const __bf16* __restrict__ WS,
                   const float* __restrict__ bias, float* __restrict__ out)
{
    __shared__ __align__(16) char Alc[2][128 * 80];
    __shared__ __align__(16) __bf16 Bl[2][256 * 32];
    constexpr int mNWG = (Mdim / 128) * (Ndim / 256);
    const int swz  = (blockIdx.x & 7) * (mNWG / 8) + (blockIdx.x >> 3);
    const int colb = swz & 3;
    const int rowb = swz >> 2;
    const int row0 = rowb * 128;
    const int tid  = threadIdx.x;
    const int lane = tid & 63;
    const int wid  = tid >> 6;
    const int wr   = wid >> 2;
    const int wcn  = wid & 3;
    const int fr   = lane & 15;
    const int hq   = lane >> 4;
    const int a_r  = tid >> 2;
    const int a_c  = (tid & 3) * 8;
    const float* Xb = X + (size_t)(row0 + a_r) * Kdim + a_c;
    const __bf16* WSb = WS + (size_t)colb * 262144;
    f32x4 ra[2];
    auto GLA = [&](int kt) {
        const float* p = Xb + kt * 32;
        ra[0] = *(const f32x4*)p;
        ra[1] = *(const f32x4*)(p + 4);
    };
    auto DSWA = [&](int buf) {
        bf16x8 v;
#pragma unroll
        for (int e = 0; e < 4; ++e) {
            v[e] = (__bf16)ra[0][e]; v[e + 4] = (__bf16)ra[1][e];
        }
        *(bf16x8*)(&Alc[buf][a_r * 80 + a_c * 2]) = v;
    };
    auto GLB = [&](int buf, int kt) {
        const __bf16* s = WSb + (size_t)kt * 8192 + wid * 1024 + lane * 8;
        gload16(s,       &Bl[buf][wid * 1024]);
        gload16(s + 512, &Bl[buf][wid * 1024 + 512]);
    };
    auto lda = [&](int buf, int i) -> bf16x8 {
        const int row = wr * 64 + i * 16 + fr;
        return *(const bf16x8*)(&Alc[buf][row * 80 + hq * 16]);
    };
    auto ldb = [&](int buf, int j) -> bf16x8 {
        return *(const bf16x8*)(&Bl[buf][(wcn * 4 + j) * 512 + lane * 8]);
    };
    f32x4 acc[4][4] = {};
    GLA(0); GLB(0, 0); DSWA(0);
    __syncthreads();
    int cur = 0;
    for (int t = 0; t < 32; ++t) {
        const int nxt = cur ^ 1;
        const bool pre = (t + 1 < 32);
        if (pre) { GLA(t + 1); GLB(nxt, t + 1); }
        bf16x8 af[4];
#pragma unroll
        for (int i = 0; i < 4; ++i) af[i] = lda(cur, i);
        __builtin_amdgcn_s_setprio(1);
#pragma unroll
        for (int j = 0; j < 4; ++j) {
            bf16x8 bfr = ldb(cur, j);
#pragma unroll
            for (int i = 0; i < 4; ++i)
                acc[i][j] = mfma16(af[i], bfr, acc[i][j]);
        }
        __builtin_amdgcn_s_setprio(0);
        if (pre) { DSWA(nxt); __syncthreads(); }
        cur = nxt;
    }
    const int orow = row0 + wr * 64 + hq * 4;
    const int ocol = colb * 256 + wcn * 64 + fr;
#pragma unroll
    for (int j = 0; j < 4; ++j) {
        const float bv = bias[ocol + j * 16];
#pragma unroll
        for (int i = 0; i < 4; ++i)
#pragma unroll
            for (int r = 0; r < 4; ++r)
                out[(size_t)(orow + i * 16 + r) * Ndim + (ocol + j * 16)] =
                    acc[i][j][r] + bv;
    }
}

__global__ __launch_bounds__(256)
void binlin_fallback(const float* __restrict__ X, const float* __restrict__ Wf,
                     const float* __restrict__ bias, float* __restrict__ out)
{
    __shared__ __align__(16) __bf16 Al[2][128][32];
    __shared__ __align__(16) __bf16 Bl[2][128][32];
    const int swz  = (blockIdx.x & 7) * (4096 / 8) + (blockIdx.x >> 3);
    const int colb = swz & 7, rowb = swz >> 3;
    const int row0 = rowb * 128, col0 = colb * 128;
    const int tid = threadIdx.x, lane = tid & 63, wid = tid >> 6;
    const int wr = wid >> 1, wc = wid & 1;
    const int sr = tid >> 2, sc = (tid & 3) * 8;
    const float* Xb = X + (size_t)row0 * Kdim;
    const float* Wb = Wf + (size_t)col0 * Kdim;
    f32x4 ra[2][2], rb[2][2];
    auto GL = [&](int k0) {
#pragma unroll
        for (int p = 0; p < 2; ++p) {
            const float* sa = Xb + (size_t)(p * 64 + sr) * Kdim + k0 + sc;
            ra[p][0] = *(const f32x4*)sa; ra[p][1] = *(const f32x4*)(sa + 4);
            const float* sb = Wb + (size_t)(p * 64 + sr) * Kdim + k0 + sc;
            rb[p][0] = *(const f32x4*)sb; rb[p][1] = *(const f32x4*)(sb + 4);
        }
    };
    auto DSW = [&](int buf) {
#pragma unroll
        for (int p = 0; p < 2; ++p) {
            bf16x8 va, vb;
#pragma unroll
            for (int e = 0; e < 4; ++e) {
                va[e] = (__bf16)ra[p][0][e]; va[e + 4] = (__bf16)ra[p][1][e];
                float a = rb[p][0][e], b = rb[p][1][e];
                vb[e] = (__bf16)(float)((a > 0.f) - (a < 0.f));
                vb[e + 4] = (__bf16)(float)((b > 0.f) - (b < 0.f));
            }
            *(bf16x8*)&Al[buf][p * 64 + sr][sc] = va;
            *(bf16x8*)&Bl[buf][p * 64 + sr][sc] = vb;
        }
    };
    f32x4 acc[4][4] = {};
    const int fr = lane & 15, ks = (lane >> 4) * 8;
    auto COMP = [&](int buf) {
        bf16x8 af[4], bf[4];
#pragma unroll
        for (int i = 0; i < 4; ++i) af[i] = *(const bf16x8*)&Al[buf][wr * 64 + fr + i * 16][ks];
#pragma unroll
        for (int j = 0; j < 4; ++j) bf[j] = *(const bf16x8*)&Bl[buf][wc * 64 + fr + j * 16][ks];
#pragma unroll
        for (int i = 0; i < 4; ++i)
#pragma unroll
            for (int j = 0; j < 4; ++j)
                acc[i][j] = mfma16(af[i], bf[j], acc[i][j]);
    };
    GL(0); DSW(0); __syncthreads();
    int cur = 0;
    for (int t = 0; t < 32; ++t) {
        if (t + 1 < 32) GL((t + 1) * 32);
        COMP(cur);
        if (t + 1 < 32) { DSW(cur ^ 1); __syncthreads(); cur ^= 1; }
    }
    const int orow = row0 + wr * 64 + (lane >> 4) * 4;
    const int ocol = col0 + wc * 64 + fr;
#pragma unroll
    for (int j = 0; j < 4; ++j) {
        const float bv = bias[ocol + j * 16];
#pragma unroll
        for (int i = 0; i < 4; ++i)
#pragma unroll
            for (int r = 0; r < 4; ++r)
                out[(size_t)(orow + i * 16 + r) * Ndim + (ocol + j * 16)] = acc[i][j][r] + bv;
    }
}

extern "C" void kernel_launch(void* const* d_in, const int* in_sizes, int n_in,
                              void* d_out, int out_size, void* d_ws, size_t ws_size,
                              hipStream_t stream) {
    const float* x  = (const float*)d_in[0];
    const float* w  = (const float*)d_in[1];
    const float* b  = (const float*)d_in[2];
    float* out      = (float*)d_out;

    constexpr size_t WI_BYTES = (size_t)Ndim * Kdim;            // 1 MB (i8)
    constexpr size_t SC_BYTES = (size_t)Mdim * sizeof(float);   // 256 KB
    constexpr size_t XI_BYTES = (size_t)Mdim * Kdim;            // 64 MB (i8)
    constexpr size_t I8_TOTAL = WI_BYTES + SC_BYTES + XI_BYTES; // ~65.3 MB
    constexpr size_t WS_BYTES = (size_t)Ndim * Kdim * sizeof(__bf16); // 2 MB

    if (ws_size >= I8_TOTAL) {
        char*  wi = (char*)d_ws;
        float* sc = (float*)((char*)d_ws + WI_BYTES);
        char*  xi = (char*)d_ws + WI_BYTES + SC_BYTES;
        wsign8_kernel<<<dim3(256),   dim3(256), 0, stream>>>(w, wi);
        xquant_kernel<<<dim3(16384), dim3(256), 0, stream>>>(x, xi, sc);
        binlin_i8r3<<<dim3(2048), dim3(512), 0, stream>>>(xi, wi, sc, b, out);
    } else if (ws_size >= WS_BYTES) {
        __bf16* ws = (__bf16*)d_ws;
        wprep_kernel<<<dim3(512), dim3(256), 0, stream>>>(w, ws);
        binlin128x256<<<dim3(2048), dim3(512), 0, stream>>>(x, ws, b, out);
    } else {
        binlin_fallback<<<dim3(4096), dim3(256), 0, stream>>>(x, w, b, out);
    }
}